// Round 3
// baseline (405.702 us; speedup 1.0000x reference)
//
#include <hip/hip_runtime.h>

// BlockMaskGenerator: B=8192, NUM_BLOCKS=4, H=W=64, S=4096.
// Outputs (int32, concatenated): context[B*S], target[B*S], positions[B*S], counts[B].
//
// v4: BARRIER-FREE wave-per-row structure + nontemporal stores.
//  - Block = 256 threads = 4 waves; wave w owns batch row b = blockIdx.x*4+w.
//  - Lane owns one full image row (64 positions) -> membership is one 64-bit
//    row mask; partition scan is wave-local (shfl only). ZERO __syncthreads.
//  - Each wave scatters into its PRIVATE skewed LDS region (2 lanes/bank) and
//    reads it back itself (same-wave ds ordering via lgkmcnt; no cross-wave dep).
//  - All global stores nontemporal (don't allocate 402 MB of dead lines in L2).
//  - History: v1/v2 VALU diet = null; v3 LDS skew = null -> kernel is bound by
//    the store path/schedule; this version makes the store stream continuous.

#define NBLK 4
#define HGT 64
#define WID 64
#define SEQ 4096
#define SKEW(a) ((a) + ((a) >> 5))
#define WROW (SEQ + (SEQ >> 5))   // 4224 skewed dword slots per wave

typedef int v4i __attribute__((ext_vector_type(4)));

__global__ __launch_bounds__(256) void blockmask_kernel(
    const float* __restrict__ scales,
    const float* __restrict__ rand_tops,
    const float* __restrict__ rand_lefts,
    int* __restrict__ out, int B)
{
    __shared__ int pos_s[4 * WROW];   // 66 KiB: private region per wave

    const int tid  = threadIdx.x;
    const int lane = tid & 63;
    const int wv   = tid >> 6;
    const int b    = blockIdx.x * 4 + wv;
    if (b >= B) return;               // no barriers anywhere -> safe early exit

    // --- per-row rectangles ---
    int top[NBLK], bot[NBLK];
    unsigned long long cmask[NBLK];
#pragma unroll
    for (int j = 0; j < NBLK; ++j) {
        int t = b * NBLK + j;
        float sc = scales[t];
        float s = __fadd_rn(0.15f, __fmul_rn(sc, 0.05f));           // no FMA contraction
        int area = (int)__fmul_rn(__fmul_rn(s, 64.0f), 64.0f);      // trunc
        int bh = (int)__fsqrt_rn((float)area);                      // IEEE sqrt, trunc
        bh = min(max(bh, 1), HGT);
        int bw = (int)__fdiv_rn((float)area, (float)bh);            // IEEE div, trunc
        bw = min(max(bw, 1), WID);
        int maxt = max(HGT - bh + 1, 1);
        int maxl = max(WID - bw + 1, 1);
        int tp = (int)__fmul_rn(rand_tops[t],  (float)maxt);
        int lf = (int)__fmul_rn(rand_lefts[t], (float)maxl);
        top[j] = tp; bot[j] = tp + bh;
        unsigned long long m = (bw >= 64) ? ~0ull : ((1ull << bw) - 1ull);
        cmask[j] = m << lf;
    }

    // --- lane owns image row r = lane: 64-bit membership mask ---
    unsigned long long rm = 0ull;
#pragma unroll
    for (int j = 0; j < NBLK; ++j)
        if (lane >= top[j] && lane < bot[j]) rm |= cmask[j];
    const int cnt = __popcll(rm);

    // --- wave-local inclusive scan (no LDS, no barrier) ---
    int v = cnt;
#pragma unroll
    for (int d = 1; d < 64; d <<= 1) {
        int t = __shfl_up(v, d, 64);
        if (lane >= d) v += t;
    }
    const int total  = __shfl(v, 63, 64);
    const int base_t = v - cnt;               // targets before p0
    const int p0     = lane * 64;
    const int base_n = total + (p0 - base_t); // total + nontargets before p0

    // --- branchless stable-partition scatter into private skewed LDS ---
    int* __restrict__ ps = pos_s + wv * WROW;
#pragma unroll
    for (int k = 0; k < 64; ++k) {
        int bit  = (int)((rm >> k) & 1ull);
        int tpre = __popcll(rm & ((1ull << k) - 1ull));   // independent per k (ILP)
        int addr = bit ? (base_t + tpre) : (base_n + k - tpre);
        ps[SKEW(addr)] = p0 + k;
    }

    // --- mask stores: wave writes its whole row, nontemporal, coalesced ---
    const size_t BS = (size_t)B * SEQ;
    v4i* ctx4 = (v4i*)out        + (size_t)b * (SEQ / 4);
    v4i* tgt4 = (v4i*)(out + BS) + (size_t)b * (SEQ / 4);
#pragma unroll
    for (int g = 0; g < 16; ++g) {
        int vidx = g * 64 + lane;
        int rr = vidx >> 4;            // image row of this 4-wide strip
        int cc = (vidx & 15) * 4;      // starting column
        unsigned long long rmg = 0ull;
#pragma unroll
        for (int j = 0; j < NBLK; ++j)
            if (rr >= top[j] && rr < bot[j]) rmg |= cmask[j];
        int m4 = (int)((rmg >> cc) & 0xfull);
        v4i tv = { m4 & 1, (m4 >> 1) & 1, (m4 >> 2) & 1, (m4 >> 3) & 1 };
        v4i cv = { tv.x ^ 1, tv.y ^ 1, tv.z ^ 1, tv.w ^ 1 };
        __builtin_nontemporal_store(tv, &tgt4[vidx]);
        __builtin_nontemporal_store(cv, &ctx4[vidx]);
    }

    // --- positions: read back own wave's LDS region, nontemporal stores ---
    // (same-wave ds_write -> ds_read ordering; compiler emits lgkmcnt wait)
    v4i* pout4 = (v4i*)(out + 2 * BS) + (size_t)b * (SEQ / 4);
#pragma unroll
    for (int g = 0; g < 16; ++g) {
        int vidx  = g * 64 + lane;
        int slot0 = vidx * 4;
        int base  = SKEW(slot0);       // slot0%32 <= 28: 4 dwords stay contiguous
        v4i pv = { ps[base + 0], ps[base + 1], ps[base + 2], ps[base + 3] };
        __builtin_nontemporal_store(pv, &pout4[vidx]);
    }

    if (lane == 0) out[3 * BS + (size_t)b] = total;
}

extern "C" void kernel_launch(void* const* d_in, const int* in_sizes, int n_in,
                              void* d_out, int out_size, void* d_ws, size_t ws_size,
                              hipStream_t stream) {
    const float* scales     = (const float*)d_in[0];
    const float* rand_tops  = (const float*)d_in[1];
    const float* rand_lefts = (const float*)d_in[2];
    int* out = (int*)d_out;
    int B = in_sizes[0] / NBLK;       // 32768/4 = 8192
    blockmask_kernel<<<(B + 3) / 4, 256, 0, stream>>>(scales, rand_tops, rand_lefts, out, B);
}